// Round 5
// baseline (211.196 us; speedup 1.0000x reference)
//
#include <hip/hip_runtime.h>

// Problem constants (from reference setup_inputs)
#define BB 8
#define CC 3
#define HH 512
#define WW 1024
#define HW (HH * WW)            // 524288 = 2^19
#define NTOT (BB * HW)          // 4194304
#define SAME_RANGE 0.2f

// Partition of (source -> target) pairs:
//   displacement <= R in both coords  -> tile owning the TARGET via 40x40 halo
//   displacement  > R in either coord -> exact outlier list (~57 of 4.2M)
#define R 4
#define TX 32
#define TY 32
#define TT (TX * TY)            // 1024 targets per block
#define RX (TX + 2 * R)         // 40 halo cols  (= 10 float4 groups, 16B aligned)
#define RY (TY + 2 * R)         // 40 halo rows
#define NG (10 * RY)            // 400 float4 groups per block
#define CELLS 8                 // 2 groups x 4 cells per thread
#define CAP 16384               // outlier list capacity (~57 used)
#define D_SENTINEL 0x7F7F7F7F   // > any depth bit pattern (depth in [0,1))

// Pass 1 (vectorized): outlier sources appended to global list.
__global__ void prep_kernel(const float* __restrict__ flow,
                            const float* __restrict__ depth,
                            const float* __restrict__ obj,
                            int* __restrict__ counter,
                            float* __restrict__ list) {
    int i = blockIdx.x * blockDim.x + threadIdx.x;   // one float4 group (4 px)
    int b = i >> 17;                                 // (4i) / HW
    int rem = (i << 2) & (HW - 1);                   // 4-aligned source offset
    int y = rem >> 10;
    int x0 = rem & (WW - 1);
    const float4 fx4 = *(const float4*)(flow + (size_t)(b * 2 + 0) * HW + rem);
    const float4 fy4 = *(const float4*)(flow + (size_t)(b * 2 + 1) * HW + rem);
    const float fxs[4] = {fx4.x, fx4.y, fx4.z, fx4.w};
    const float fys[4] = {fy4.x, fy4.y, fy4.z, fy4.w};
    #pragma unroll
    for (int k = 0; k < 4; ++k) {
        int x = x0 + k;
        float px = fminf(fmaxf(fxs[k] + (float)x, 0.0f), (float)(WW - 1));
        float py = fminf(fmaxf(fys[k] + (float)y, 0.0f), (float)(HH - 1));
        int xi = (int)rintf(px);    // round-half-to-even == jnp.round
        int yi = (int)rintf(py);
        int dx = xi - x; if (dx < 0) dx = -dx;
        int dy = yi - y; if (dy < 0) dy = -dy;
        if (dx > R || dy > R) {
            int idx = b * HW + yi * WW + xi;
            int srem = rem + k;
            float d = depth[(size_t)b * HW + srem];
            int pos = atomicAdd(counter, 1);
            if (pos < CAP) {
                float* e = list + (size_t)pos * 8;
                e[0] = __int_as_float(idx);
                e[1] = d;
                e[2] = obj[((size_t)b * CC + 0) * HW + srem];
                e[3] = obj[((size_t)b * CC + 1) * HW + srem];
                e[4] = obj[((size_t)b * CC + 2) * HW + srem];
            }
        }
    }
}

// Pass 2: LDS-scatter gather, fully float4-vectorized loads, obj prefetched
// in phase 1 (before the barrier) so phase 2 has no dependent global loads.
__global__ __launch_bounds__(256) void gather_kernel(
        const float* __restrict__ obj,
        const float* __restrict__ flow,
        const float* __restrict__ depth,
        const int* __restrict__ counter,
        const float* __restrict__ list,
        float* __restrict__ out) {
    __shared__ int   s_dmin[TT];
    __shared__ float s_s0[TT], s_s1[TT], s_s2[TT], s_cnt[TT];

    const int b   = blockIdx.z;
    const int tx0 = blockIdx.x * TX;
    const int ty0 = blockIdx.y * TY;
    const int tid = threadIdx.x;

    #pragma unroll
    for (int i = tid; i < TT; i += 256) {
        s_dmin[i] = D_SENTINEL;
        s_s0[i] = 0.0f; s_s1[i] = 0.0f; s_s2[i] = 0.0f; s_cnt[i] = 0.0f;
    }
    __syncthreads();

    // Per-cell state carried to phase 2 (registers; fully unrolled indexing).
    int   tloc[CELLS];
    float dep[CELLS];
    float o0[CELLS], o1[CELLS], o2[CELLS];

    // Phase 1: 6 float4 loads per group; compute targets; LDS z-buffer min.
    #pragma unroll
    for (int e = 0; e < 2; ++e) {
        #pragma unroll
        for (int k = 0; k < 4; ++k) tloc[e * 4 + k] = -1;
        int g = tid + e * 256;
        if (g < NG) {
            int row = g / 10;
            int col = g - row * 10;
            int gy = ty0 - R + row;
            int x0 = tx0 - R + col * 4;      // 16B aligned; never straddles edge
            if (gy >= 0 && gy < HH && x0 >= 0 && x0 < WW) {
                size_t roff = (size_t)gy * WW + x0;
                const float4 fx4 = *(const float4*)(flow + (size_t)(b * 2 + 0) * HW + roff);
                const float4 fy4 = *(const float4*)(flow + (size_t)(b * 2 + 1) * HW + roff);
                const float4 d4  = *(const float4*)(depth + (size_t)b * HW + roff);
                const float4 a0  = *(const float4*)(obj + ((size_t)b * CC + 0) * HW + roff);
                const float4 a1  = *(const float4*)(obj + ((size_t)b * CC + 1) * HW + roff);
                const float4 a2  = *(const float4*)(obj + ((size_t)b * CC + 2) * HW + roff);
                const float fxs[4] = {fx4.x, fx4.y, fx4.z, fx4.w};
                const float fys[4] = {fy4.x, fy4.y, fy4.z, fy4.w};
                const float ds[4]  = {d4.x, d4.y, d4.z, d4.w};
                const float a0s[4] = {a0.x, a0.y, a0.z, a0.w};
                const float a1s[4] = {a1.x, a1.y, a1.z, a1.w};
                const float a2s[4] = {a2.x, a2.y, a2.z, a2.w};
                #pragma unroll
                for (int k = 0; k < 4; ++k) {
                    int x = x0 + k;
                    float px = fminf(fmaxf(fxs[k] + (float)x, 0.0f), (float)(WW - 1));
                    float py = fminf(fmaxf(fys[k] + (float)gy, 0.0f), (float)(HH - 1));
                    int xi = (int)rintf(px);
                    int yi = (int)rintf(py);
                    int ddx = xi - x;  if (ddx < 0) ddx = -ddx;
                    int ddy = yi - gy; if (ddy < 0) ddy = -ddy;
                    // displacement <= R only: outliers handled EXCLUSIVELY by list
                    if (ddx <= R && ddy <= R) {
                        int lx = xi - tx0;
                        int ly = yi - ty0;
                        if (lx >= 0 && lx < TX && ly >= 0 && ly < TY) {
                            int t = ly * TX + lx;
                            int c = e * 4 + k;
                            tloc[c] = t;
                            dep[c]  = ds[k];
                            o0[c] = a0s[k]; o1[c] = a1s[k]; o2[c] = a2s[k];
                            atomicMin(&s_dmin[t], __float_as_int(ds[k]));
                        }
                    }
                }
            }
        }
    }

    // Outlier phase 1: fold list depths into the LDS z-buffer.
    int noutl = *counter;
    if (noutl > CAP) noutl = CAP;
    for (int j = tid; j < noutl; j += 256) {
        const float* e = list + (size_t)j * 8;
        int idx = __float_as_int(e[0]);
        if ((idx >> 19) == b) {
            int remt = idx & (HW - 1);
            int lx = (remt & (WW - 1)) - tx0;
            int ly = (remt >> 10) - ty0;
            if (lx >= 0 && lx < TX && ly >= 0 && ly < TY)
                atomicMin(&s_dmin[ly * TX + lx], __float_as_int(e[1]));
        }
    }
    __syncthreads();

    // Phase 2: keep-test + accumulate. All operands already in registers.
    #pragma unroll
    for (int c = 0; c < CELLS; ++c) {
        if (tloc[c] >= 0) {
            float thresh = __int_as_float(s_dmin[tloc[c]]) + SAME_RANGE;
            if (dep[c] <= thresh) {
                atomicAdd(&s_s0[tloc[c]], o0[c]);
                atomicAdd(&s_s1[tloc[c]], o1[c]);
                atomicAdd(&s_s2[tloc[c]], o2[c]);
                atomicAdd(&s_cnt[tloc[c]], 1.0f);
            }
        }
    }
    // Outlier phase 2.
    for (int j = tid; j < noutl; j += 256) {
        const float* e = list + (size_t)j * 8;
        int idx = __float_as_int(e[0]);
        if ((idx >> 19) == b) {
            int remt = idx & (HW - 1);
            int lx = (remt & (WW - 1)) - tx0;
            int ly = (remt >> 10) - ty0;
            if (lx >= 0 && lx < TX && ly >= 0 && ly < TY) {
                int t = ly * TX + lx;
                float thresh = __int_as_float(s_dmin[t]) + SAME_RANGE;
                if (e[1] <= thresh) {
                    atomicAdd(&s_s0[t], e[2]);
                    atomicAdd(&s_s1[t], e[3]);
                    atomicAdd(&s_s2[t], e[4]);
                    atomicAdd(&s_cnt[t], 1.0f);
                }
            }
        }
    }
    __syncthreads();

    // Phase 3: divide + float4 coalesced store (one group per thread/channel).
    {
        int r  = tid >> 3;            // 0..31 tile row
        int gc = (tid & 7) * 4;       // 0,4,...,28 tile col group
        int lbase = r * TX + gc;
        size_t orem = (size_t)(ty0 + r) * WW + tx0 + gc;
        float cn[4], s0v[4], s1v[4], s2v[4];
        #pragma unroll
        for (int k = 0; k < 4; ++k) {
            cn[k]  = s_cnt[lbase + k];
            s0v[k] = s_s0[lbase + k];
            s1v[k] = s_s1[lbase + k];
            s2v[k] = s_s2[lbase + k];
        }
        float4 r0, r1, r2;
        float* p0 = &r0.x; float* p1 = &r1.x; float* p2 = &r2.x;
        #pragma unroll
        for (int k = 0; k < 4; ++k) {
            if (cn[k] > 0.0f) {
                p0[k] = s0v[k] / cn[k];
                p1[k] = s1v[k] / cn[k];
                p2[k] = s2v[k] / cn[k];
            } else {
                p0[k] = 0.0f; p1[k] = 0.0f; p2[k] = 0.0f;
            }
        }
        *(float4*)(out + ((size_t)b * CC + 0) * HW + orem) = r0;
        *(float4*)(out + ((size_t)b * CC + 1) * HW + orem) = r1;
        *(float4*)(out + ((size_t)b * CC + 2) * HW + orem) = r2;
    }
}

extern "C" void kernel_launch(void* const* d_in, const int* in_sizes, int n_in,
                              void* d_out, int out_size, void* d_ws, size_t ws_size,
                              hipStream_t stream) {
    const float* obj   = (const float*)d_in[0];
    const float* flow  = (const float*)d_in[1];
    const float* depth = (const float*)d_in[2];
    float* out = (float*)d_out;

    int*   counter = (int*)d_ws;
    float* list    = (float*)((char*)d_ws + 256);

    hipMemsetAsync(counter, 0, sizeof(int), stream);

    prep_kernel<<<dim3(NTOT / 4 / 256), dim3(256), 0, stream>>>(
        flow, depth, obj, counter, list);

    gather_kernel<<<dim3(WW / TX, HH / TY, BB), dim3(256), 0, stream>>>(
        obj, flow, depth, counter, list, out);
}